// Round 3
// baseline (210.317 us; speedup 1.0000x reference)
//
#include <hip/hip_runtime.h>

#define Bsz 128
#define Wd 19
#define Hd 19
#define Ad 5
#define Cd 81
#define Md 24
#define Nd (Wd*Hd)        // 361
#define NAd (Nd*Ad)       // 1805
#define TOTPOS (Bsz*NAd)  // 231040
#define PPB 64            // positions per sweep block; TOTPOS/PPB = 3610 blocks
#define EPSF 1e-7f
#define IOU_THRF 0.6f

// ws float layout:
//   [0..4)          acc: 0=noobj, 1=obj, 2=xy, 3=wh
//   [4..1809)       gtsum[NAd]
//   [1809..3614)    corr[NAd]   (assign's CE corrections)
//   [4096..235136)  ce_full[TOTPOS]  (written by sweep, no init needed)
#define OFF_GT   4
#define OFF_CORR (4 + NAd)
#define OFF_CE   4096
#define MEMSET_FLOATS (4 + 2*NAd)

// 3072 objects: 96 blocks x 4 waves x 8 objects. One wave per object-batch:
// coalesced one-hot label read + shuffle dot; per-object tail on lane 0;
// block-level reduction -> 4 global atomics per block (384 total).
__global__ __launch_bounds__(256) void yolo_assign(
        const float* __restrict__ conf,
        const float* __restrict__ pred_xy,
        const float* __restrict__ pred_wh,
        const float* __restrict__ cls_score,
        const float* __restrict__ true_label,
        const float* __restrict__ true_object,
        float* __restrict__ ws) {
    const float AW[5] = {0.57273f, 1.87446f, 3.33843f, 7.88282f, 9.77052f};
    const float AH[5] = {0.677385f, 2.06253f, 5.47434f, 3.52778f, 9.16828f};
    int wave = threadIdx.x >> 6, lane = threadIdx.x & 63;
    float a0 = 0.f, a1 = 0.f, a2 = 0.f, a3 = 0.f;
    float* gtsum = ws + OFF_GT;
    float* corr  = ws + OFF_CORR;

    int objBase = (blockIdx.x * 4 + wave) * 8;
    for (int o = 0; o < 8; o++) {
        int idx = objBase + o;
        // coalesced one-hot -> label index (wave dot with iota)
        const float* tl = true_label + (size_t)idx * Cd;
        float labf = tl[lane] * (float)lane;
        if (lane < Cd - 64) labf += tl[64 + lane] * (float)(64 + lane);
        #pragma unroll
        for (int off = 32; off > 0; off >>= 1) labf += __shfl_down(labf, off, 64);

        if (lane == 0) {
            int lab = (int)(labf + 0.5f);
            int b = idx / Md;
            const float4 to = ((const float4*)true_object)[idx];
            const float inv_ds = 1.0f / 32.0f;
            float gx = to.x * inv_ds, gy = to.y * inv_ds;
            float gw = to.z * inv_ds, gh = to.w * inv_ds;
            int ci = (int)gy, cj = (int)gx;          // trunc == astype(int32)
            int cell = ci * Hd + cj;
            float garea = gw * gh;

            float best_iou = -1.0f; int best = 0; bool over[Ad];
            #pragma unroll
            for (int a = 0; a < Ad; a++) {
                float inter = fminf(AW[a], gw) * fminf(AH[a], gh);
                float iou = inter / (AW[a] * AH[a] + garea - inter + EPSF);
                over[a] = iou > IOU_THRF;
                if (iou > best_iou) { best_iou = iou; best = a; }
            }

            int base_bn = (b * Nd + cell) * Ad;
            float pwb = pred_wh[(size_t)(base_bn + best) * 2 + 0];
            float phb = pred_wh[(size_t)(base_bn + best) * 2 + 1];
            float inter = fminf(pwb, gw) * fminf(phb, gh);
            float iou_pg = inter / (pwb * phb + garea - inter + EPSF);
            float sw = 2.0f - (gw * (1.0f / 19.0f)) * (gh * (1.0f / 19.0f));

            #pragma unroll
            for (int a = 0; a < Ad; a++) {
                bool isb = (a == best);
                if (!(isb || over[a])) continue;     // om == 0 -> nothing
                int pos = base_bn + a;
                int na  = cell * Ad + a;
                float cp = fminf(fmaxf(conf[pos], EPSF), 1.0f - EPSF);
                a0 += __logf(1.0f - cp);             // cancel base noobj term
                const float* cs = cls_score + (size_t)pos * Cd;
                atomicAdd(&corr[na], cs[Cd - 1] - cs[lab]);
                if (isb) {
                    atomicAdd(&gtsum[na], 1.0f);
                    a1 += -(iou_pg * __logf(cp) + (1.0f - iou_pg) * __logf(1.0f - cp));
                    float px = pred_xy[(size_t)pos * 2 + 0], py = pred_xy[(size_t)pos * 2 + 1];
                    a2 += sw * ((px - gx) * (px - gx) + (py - gy) * (py - gy));
                    float pwa = pred_wh[(size_t)pos * 2 + 0], pha = pred_wh[(size_t)pos * 2 + 1];
                    a3 += sw * ((pwa - gw) * (pwa - gw) + (pha - gh) * (pha - gh));
                }
            }
        }
    }

    // block reduce (only lane 0 of each wave holds nonzero) -> 4 atomics/block
    __shared__ float red[4][4];
    if (lane == 0) { red[wave][0] = a0; red[wave][1] = a1; red[wave][2] = a2; red[wave][3] = a3; }
    __syncthreads();
    if (threadIdx.x == 0) {
        atomicAdd(&ws[0], red[0][0] + red[1][0] + red[2][0] + red[3][0]);
        atomicAdd(&ws[1], red[0][1] + red[1][1] + red[2][1] + red[3][1]);
        atomicAdd(&ws[2], red[0][2] + red[1][2] + red[2][2] + red[3][2]);
        atomicAdd(&ws[3], red[0][3] + red[1][3] + red[2][3] + red[3][3]);
    }
}

// 3610 blocks x 256 threads, 64 positions/block. Per-wave self-contained:
// wave w stages float4s [w*324, (w+1)*324) of the block chunk (5 full-exec
// rounds + 1 overlapping full-exec tail window -> all 64 lanes always active),
// then reduces its own 16 positions from LDS (exp applied here). ce written
// non-atomically: flat (b,na) index == flat position index.
__global__ __launch_bounds__(256) void yolo_sweep(
        const float* __restrict__ conf,
        const float* __restrict__ cls_score,
        float* __restrict__ ws) {
    __shared__ float ex[PPB * Cd];                 // 20,736 B -> 7 blocks/CU
    const int tid = threadIdx.x, bid = blockIdx.x;
    const int wave = tid >> 6, lane = tid & 63;
    const int base = wave * 324;                   // float4 index within block chunk

    const float4* g = (const float4*)(cls_score + (size_t)bid * (PPB * Cd));
    float4* l4 = (float4*)ex;

    // issue all 6 loads up-front (independent -> deep MLP)
    float4 r0 = g[base + 0 * 64 + lane];
    float4 r1 = g[base + 1 * 64 + lane];
    float4 r2 = g[base + 2 * 64 + lane];
    float4 r3 = g[base + 3 * 64 + lane];
    float4 r4 = g[base + 4 * 64 + lane];
    float4 r5 = g[base + 260 + lane];              // overlap tail [260,324)

    float nb = 0.0f;
    if (tid < PPB) {
        float cp = fminf(fmaxf(conf[bid * PPB + tid], EPSF), 1.0f - EPSF);
        nb = -__logf(1.0f - cp);
    }

    l4[base + 0 * 64 + lane] = r0;
    l4[base + 1 * 64 + lane] = r1;
    l4[base + 2 * 64 + lane] = r2;
    l4[base + 3 * 64 + lane] = r3;
    l4[base + 4 * 64 + lane] = r4;
    l4[base + 260 + lane] = r5;                    // duplicate writes, same data
    __syncthreads();

    // 4 threads per position; wave w reads only positions [w*16, w*16+16)
    int pos = tid >> 2, h = tid & 3;
    const float* p = ex + pos * Cd;
    int c0 = h * 20, c1 = (h == 3) ? Cd : c0 + 20;
    float s = 0.0f;
    for (int c = c0; c < c1; c++) s += __expf(p[c]);
    s += __shfl_xor(s, 1, 64);
    s += __shfl_xor(s, 2, 64);
    if (h == 0) {
        float ce = __logf(s) - p[Cd - 1];          // log(sum exp) - raw cs[80]
        ws[OFF_CE + bid * PPB + pos] = ce;         // non-atomic, coalesced
    }

    // noobj: only wave 0 holds nonzero -> 1 atomic per block
    if (wave == 0) {
        #pragma unroll
        for (int off = 32; off > 0; off >>= 1) nb += __shfl_down(nb, off, 64);
        if (lane == 0) atomicAdd(&ws[0], nb);
    }
}

__global__ __launch_bounds__(1024) void yolo_finalize(
        const float* __restrict__ ws, float* __restrict__ out) {
    __shared__ float red[16];
    const float* gtsum = ws + OFF_GT;
    const float* corr  = ws + OFF_CORR;
    const float* cef   = ws + OFF_CE;
    float s = 0.0f;
    for (int na = threadIdx.x; na < NAd; na += 1024) {
        float sum = corr[na];
        const float* col = cef + na;
        #pragma unroll 4
        for (int b = 0; b < Bsz; b++) sum += col[(size_t)b * NAd];
        s += gtsum[na] * sum;
    }
    #pragma unroll
    for (int off = 32; off > 0; off >>= 1) s += __shfl_down(s, off, 64);
    if ((threadIdx.x & 63) == 0) red[threadIdx.x >> 6] = s;
    __syncthreads();
    if (threadIdx.x == 0) {
        float tot = 0.f;
        #pragma unroll
        for (int i = 0; i < 16; i++) tot += red[i];
        const float invB = 1.0f / (float)Bsz;
        float noobj = 1.0f * ws[0] * invB;   // SCALE_NOOBJ = 1
        float obj   = 5.0f * ws[1] * invB;
        float xy    = 5.0f * ws[2] * invB;
        float wh    = 5.0f * ws[3] * invB;
        float score = 5.0f * tot  * invB;
        out[0] = noobj + obj + xy + wh + score;
        out[1] = noobj;
        out[2] = obj;
        out[3] = score;
        out[4] = xy;
        out[5] = wh;
    }
}

extern "C" void kernel_launch(void* const* d_in, const int* in_sizes, int n_in,
                              void* d_out, int out_size, void* d_ws, size_t ws_size,
                              hipStream_t stream) {
    // inputs: 0=epoch(unused), 1=conf, 2=pred_xy, 3=pred_wh, 4=cls_score,
    //         5=true_label, 6=true_object, 7=fm_cord(unused - cancels out)
    const float* conf    = (const float*)d_in[1];
    const float* pred_xy = (const float*)d_in[2];
    const float* pred_wh = (const float*)d_in[3];
    const float* cls     = (const float*)d_in[4];
    const float* tlabel  = (const float*)d_in[5];
    const float* tobject = (const float*)d_in[6];
    float* ws  = (float*)d_ws;
    float* out = (float*)d_out;

    hipMemsetAsync(ws, 0, MEMSET_FLOATS * sizeof(float), stream);

    yolo_sweep<<<TOTPOS / PPB, 256, 0, stream>>>(conf, cls, ws);

    yolo_assign<<<96, 256, 0, stream>>>(conf, pred_xy, pred_wh, cls, tlabel, tobject, ws);

    yolo_finalize<<<1, 1024, 0, stream>>>(ws, out);
}

// Round 4
// 165.431 us; speedup vs baseline: 1.2713x; 1.2713x over previous
//
#include <hip/hip_runtime.h>

#define Bsz 128
#define Cd 81
#define Md 24
#define Nd 361
#define NAd 1805
#define TOTPOS 231040          // Bsz*NAd
#define RPW 16                 // rows per wave
#define NW_CLS (TOTPOS/RPW)    // 14440 cls waves
#define NOBJ (Bsz*Md)          // 3072
#define NW_LAB (NOBJ/RPW)      // 192 label waves
#define EPSF 1e-7f
#define IOU_THRF 0.6f

// ws float layout:
//   [0 .. 1805)            cesum[NAd]        (zeroed by memset; sweep atomics)
//   [2048 .. 2048+14440)   noobj slot/wave   (written unconditionally)
//   [17408 .. 17408+3072)  label (as float)  (written unconditionally)
#define OFF_CESUM 0
#define OFF_NOOBJ 2048
#define OFF_LAB   17408

// One wave per block: 16 rows of 81 floats = 324 float4s staged via 6
// fully-coalesced loads (5 rounds + overlapping tail window), exp in
// registers, LDS only for the segmented row-sum. No inter-wave coupling:
// ~30 independent blocks/CU. Last NW_LAB blocks process true_label rows
// computing the one-hot dot with the class index instead of sum-exp.
__global__ __launch_bounds__(64) void yolo_sweep(
        const float* __restrict__ conf,
        const float* __restrict__ cls_score,
        const float* __restrict__ true_label,
        float* __restrict__ ws) {
    __shared__ float ex[RPW * Cd];              // 5184 B
    const int bid = blockIdx.x;
    const int lane = threadIdx.x;
    const bool is_cls = bid < NW_CLS;

    const float* src = is_cls ? (cls_score + (size_t)bid * (RPW * Cd))
                              : (true_label + (size_t)(bid - NW_CLS) * (RPW * Cd));
    const float4* g = (const float4*)src;
    float4 r0 = g[0 * 64 + lane];
    float4 r1 = g[1 * 64 + lane];
    float4 r2 = g[2 * 64 + lane];
    float4 r3 = g[3 * 64 + lane];
    float4 r4 = g[4 * 64 + lane];
    float4 r5 = g[260 + lane];                  // tail overlap [260,324)

    float nb = 0.0f;
    if (is_cls) {
        if (lane < RPW) {
            float cp = fminf(fmaxf(conf[bid * RPW + lane], EPSF), 1.0f - EPSF);
            nb = -__logf(1.0f - cp);
        }
        r0.x = __expf(r0.x); r0.y = __expf(r0.y); r0.z = __expf(r0.z); r0.w = __expf(r0.w);
        r1.x = __expf(r1.x); r1.y = __expf(r1.y); r1.z = __expf(r1.z); r1.w = __expf(r1.w);
        r2.x = __expf(r2.x); r2.y = __expf(r2.y); r2.z = __expf(r2.z); r2.w = __expf(r2.w);
        r3.x = __expf(r3.x); r3.y = __expf(r3.y); r3.z = __expf(r3.z); r3.w = __expf(r3.w);
        r4.x = __expf(r4.x); r4.y = __expf(r4.y); r4.z = __expf(r4.z); r4.w = __expf(r4.w);
        r5.x = __expf(r5.x); r5.y = __expf(r5.y); r5.z = __expf(r5.z); r5.w = __expf(r5.w);
    }
    float4* l4 = (float4*)ex;
    l4[0 * 64 + lane] = r0;
    l4[1 * 64 + lane] = r1;
    l4[2 * 64 + lane] = r2;
    l4[3 * 64 + lane] = r3;
    l4[4 * 64 + lane] = r4;
    l4[260 + lane] = r5;                        // duplicates carry identical data
    __syncthreads();                            // single-wave block: ~free

    // 4 lanes per row, uniform predicated loop -> unrolled, batched ds_reads
    const int r = lane >> 2, h = lane & 3;
    const float* p = ex + r * Cd;
    float s = 0.0f;
    #pragma unroll
    for (int j = 0; j < 21; j++) {
        int c = h * 21 + j;
        int cc = c < 81 ? c : 80;               // stay in-bounds
        float w = (c < 81) ? (is_cls ? 1.0f : (float)c) : 0.0f;
        s += p[cc] * w;
    }
    s += __shfl_xor(s, 1, 64);
    s += __shfl_xor(s, 2, 64);

    if (h == 0) {
        int row = bid * RPW + r;
        if (is_cls) {
            float ce = __logf(s) - __logf(p[80]);   // log-sum-exp - raw cs[80]
            int na = row % NAd;                     // row = b*NAd + na
            atomicAdd(&ws[OFF_CESUM + na], ce);
        } else {
            ws[OFF_LAB + ((bid - NW_CLS) * RPW + r)] = s;   // label as float
        }
    }
    if (is_cls) {
        #pragma unroll
        for (int off = 32; off > 0; off >>= 1) nb += __shfl_xor(nb, off, 64);
        if (lane == 0) ws[OFF_NOOBJ + bid] = nb;    // non-atomic slot
    }
}

// Single block: per-object assignment (gt/corr in LDS via LDS atomics),
// then score dot + noobj-slot sum + final assembly. One dispatch.
__global__ __launch_bounds__(1024) void yolo_final(
        const float* __restrict__ conf,
        const float* __restrict__ pred_xy,
        const float* __restrict__ pred_wh,
        const float* __restrict__ cls_score,
        const float* __restrict__ true_object,
        const float* __restrict__ ws,
        float* __restrict__ out) {
    __shared__ float gt[NAd];
    __shared__ float corr[NAd];
    __shared__ float red[6][16];
    const float AW[5] = {0.57273f, 1.87446f, 3.33843f, 7.88282f, 9.77052f};
    const float AH[5] = {0.677385f, 2.06253f, 5.47434f, 3.52778f, 9.16828f};
    const int tid = threadIdx.x;

    for (int i = tid; i < NAd; i += 1024) { gt[i] = 0.0f; corr[i] = 0.0f; }
    __syncthreads();

    float a0 = 0.f, a1 = 0.f, a2 = 0.f, a3 = 0.f;   // noobj-cancel, obj, xy, wh
    #pragma unroll
    for (int o = 0; o < 3; o++) {
        int idx = tid + o * 1024;                   // 3072 objects exactly
        int lab = (int)(ws[OFF_LAB + idx] + 0.5f);
        int b = idx / Md;
        const float4 to = ((const float4*)true_object)[idx];
        const float inv_ds = 1.0f / 32.0f;
        float gx = to.x * inv_ds, gy = to.y * inv_ds;
        float gw = to.z * inv_ds, gh = to.w * inv_ds;
        int ci = (int)gy, cj = (int)gx;             // trunc == astype(int32)
        int cell = ci * 19 + cj;
        float garea = gw * gh;

        float best_iou = -1.0f; int best = 0; bool over[5];
        #pragma unroll
        for (int a = 0; a < 5; a++) {
            float inter = fminf(AW[a], gw) * fminf(AH[a], gh);
            float iou = inter / (AW[a] * AH[a] + garea - inter + EPSF);
            over[a] = iou > IOU_THRF;
            if (iou > best_iou) { best_iou = iou; best = a; }
        }

        int base_bn = (b * Nd + cell) * 5;
        float pwb = pred_wh[(size_t)(base_bn + best) * 2 + 0];
        float phb = pred_wh[(size_t)(base_bn + best) * 2 + 1];
        float inter = fminf(pwb, gw) * fminf(phb, gh);
        float iou_pg = inter / (pwb * phb + garea - inter + EPSF);
        float sw = 2.0f - (gw * (1.0f / 19.0f)) * (gh * (1.0f / 19.0f));

        #pragma unroll
        for (int a = 0; a < 5; a++) {
            bool isb = (a == best);
            if (!(isb || over[a])) continue;        // om == 0 -> untouched
            int pos = base_bn + a;
            int na  = cell * 5 + a;
            float cp = fminf(fmaxf(conf[pos], EPSF), 1.0f - EPSF);
            a0 += __logf(1.0f - cp);                // cancel base noobj term
            const float* cs = cls_score + (size_t)pos * Cd;
            atomicAdd(&corr[na], cs[Cd - 1] - cs[lab]);
            if (isb) {
                atomicAdd(&gt[na], 1.0f);
                a1 += -(iou_pg * __logf(cp) + (1.0f - iou_pg) * __logf(1.0f - cp));
                float px = pred_xy[(size_t)pos * 2 + 0], py = pred_xy[(size_t)pos * 2 + 1];
                a2 += sw * ((px - gx) * (px - gx) + (py - gy) * (py - gy));
                float pwa = pred_wh[(size_t)pos * 2 + 0], pha = pred_wh[(size_t)pos * 2 + 1];
                a3 += sw * ((pwa - gw) * (pwa - gw) + (pha - gh) * (pha - gh));
            }
        }
    }
    __syncthreads();

    // noobj slots + score dot, strided/coalesced
    float nsum = 0.0f;
    for (int i = tid; i < NW_CLS; i += 1024) nsum += ws[OFF_NOOBJ + i];
    float ssum = 0.0f;
    for (int na = tid; na < NAd; na += 1024)
        ssum += gt[na] * (corr[na] + ws[OFF_CESUM + na]);

    // block-reduce 6 scalars
    float v[6] = {a0, a1, a2, a3, nsum, ssum};
    #pragma unroll
    for (int k = 0; k < 6; k++) {
        float x = v[k];
        #pragma unroll
        for (int off = 32; off > 0; off >>= 1) x += __shfl_xor(x, off, 64);
        if ((tid & 63) == 0) red[k][tid >> 6] = x;
    }
    __syncthreads();
    if (tid == 0) {
        float t[6];
        #pragma unroll
        for (int k = 0; k < 6; k++) {
            float x = 0.f;
            #pragma unroll
            for (int w = 0; w < 16; w++) x += red[k][w];
            t[k] = x;
        }
        const float invB = 1.0f / (float)Bsz;
        float noobj = 1.0f * (t[4] + t[0]) * invB;   // base sum + cancels
        float obj   = 5.0f * t[1] * invB;
        float xy    = 5.0f * t[2] * invB;
        float wh    = 5.0f * t[3] * invB;
        float score = 5.0f * t[5] * invB;
        out[0] = noobj + obj + xy + wh + score;
        out[1] = noobj;
        out[2] = obj;
        out[3] = score;
        out[4] = xy;
        out[5] = wh;
    }
}

extern "C" void kernel_launch(void* const* d_in, const int* in_sizes, int n_in,
                              void* d_out, int out_size, void* d_ws, size_t ws_size,
                              hipStream_t stream) {
    // inputs: 0=epoch(unused), 1=conf, 2=pred_xy, 3=pred_wh, 4=cls_score,
    //         5=true_label, 6=true_object, 7=fm_cord(unused - cancels out)
    const float* conf    = (const float*)d_in[1];
    const float* pred_xy = (const float*)d_in[2];
    const float* pred_wh = (const float*)d_in[3];
    const float* cls     = (const float*)d_in[4];
    const float* tlabel  = (const float*)d_in[5];
    const float* tobject = (const float*)d_in[6];
    float* ws  = (float*)d_ws;
    float* out = (float*)d_out;

    hipMemsetAsync(ws + OFF_CESUM, 0, NAd * sizeof(float), stream);

    yolo_sweep<<<NW_CLS + NW_LAB, 64, 0, stream>>>(conf, cls, tlabel, ws);

    yolo_final<<<1, 1024, 0, stream>>>(conf, pred_xy, pred_wh, cls, tobject, ws, out);
}

// Round 5
// 137.725 us; speedup vs baseline: 1.5271x; 1.2012x over previous
//
#include <hip/hip_runtime.h>

#define Bsz 128
#define Cd 81
#define Md 24
#define Nd 361
#define NAd 1805
#define TOTPOS 231040          // Bsz*NAd
#define RPW 16                 // rows per wave
#define NW_CLS (TOTPOS/RPW)    // 14440 cls waves
#define NOBJ (Bsz*Md)          // 3072
#define NW_LAB (NOBJ/RPW)      // 192 label waves
#define EPSF 1e-7f
#define IOU_THRF 0.6f

// ws float layout:
//   [0 .. 1805)            cesum[NAd]   (sweep base CE + assign corrections)
//   [1808 .. 1812)         acc: 0=noobj-cancel, 1=obj, 2=xy, 3=wh
//   [1824 .. 3629)         gt[NAd]
//   [4096 .. 4096+14440)   noobj slot per sweep block (written unconditionally)
//   [20480 .. 20480+3072)  label (as float, written unconditionally)
#define OFF_CESUM 0
#define OFF_ACC   1808
#define OFF_GT    1824
#define OFF_NOOBJ 4096
#define OFF_LAB   20480
#define MEMSET_FLOATS 3629

// One wave per block: 16 rows of 81 floats = 324 float4s staged via 6
// fully-coalesced loads (5 rounds + overlapping tail window), exp in
// registers, LDS only for the segmented row-sum. No inter-wave coupling.
// Last NW_LAB blocks process true_label rows, computing the one-hot dot
// with the class index instead of sum-exp.
__global__ __launch_bounds__(64) void yolo_sweep(
        const float* __restrict__ conf,
        const float* __restrict__ cls_score,
        const float* __restrict__ true_label,
        float* __restrict__ ws) {
    __shared__ float ex[RPW * Cd];              // 5184 B
    const int bid = blockIdx.x;
    const int lane = threadIdx.x;
    const bool is_cls = bid < NW_CLS;

    const float* src = is_cls ? (cls_score + (size_t)bid * (RPW * Cd))
                              : (true_label + (size_t)(bid - NW_CLS) * (RPW * Cd));
    const float4* g = (const float4*)src;
    float4 r0 = g[0 * 64 + lane];
    float4 r1 = g[1 * 64 + lane];
    float4 r2 = g[2 * 64 + lane];
    float4 r3 = g[3 * 64 + lane];
    float4 r4 = g[4 * 64 + lane];
    float4 r5 = g[260 + lane];                  // tail overlap [260,324)

    float nb = 0.0f;
    if (is_cls) {
        if (lane < RPW) {
            float cp = fminf(fmaxf(conf[bid * RPW + lane], EPSF), 1.0f - EPSF);
            nb = -__logf(1.0f - cp);
        }
        r0.x = __expf(r0.x); r0.y = __expf(r0.y); r0.z = __expf(r0.z); r0.w = __expf(r0.w);
        r1.x = __expf(r1.x); r1.y = __expf(r1.y); r1.z = __expf(r1.z); r1.w = __expf(r1.w);
        r2.x = __expf(r2.x); r2.y = __expf(r2.y); r2.z = __expf(r2.z); r2.w = __expf(r2.w);
        r3.x = __expf(r3.x); r3.y = __expf(r3.y); r3.z = __expf(r3.z); r3.w = __expf(r3.w);
        r4.x = __expf(r4.x); r4.y = __expf(r4.y); r4.z = __expf(r4.z); r4.w = __expf(r4.w);
        r5.x = __expf(r5.x); r5.y = __expf(r5.y); r5.z = __expf(r5.z); r5.w = __expf(r5.w);
    }
    float4* l4 = (float4*)ex;
    l4[0 * 64 + lane] = r0;
    l4[1 * 64 + lane] = r1;
    l4[2 * 64 + lane] = r2;
    l4[3 * 64 + lane] = r3;
    l4[4 * 64 + lane] = r4;
    l4[260 + lane] = r5;                        // duplicates carry identical data
    __syncthreads();                            // single-wave block: ~free

    // 4 lanes per row, uniform predicated loop -> unrolled, batched ds_reads
    const int r = lane >> 2, h = lane & 3;
    const float* p = ex + r * Cd;
    float s = 0.0f;
    #pragma unroll
    for (int j = 0; j < 21; j++) {
        int c = h * 21 + j;
        int cc = c < 81 ? c : 80;               // stay in-bounds
        float w = (c < 81) ? (is_cls ? 1.0f : (float)c) : 0.0f;
        s += p[cc] * w;
    }
    s += __shfl_xor(s, 1, 64);
    s += __shfl_xor(s, 2, 64);

    if (h == 0) {
        int row = bid * RPW + r;
        if (is_cls) {
            float ce = __logf(s) - __logf(p[80]);   // log-sum-exp - raw cs[80]
            int na = row % NAd;                     // row = b*NAd + na
            atomicAdd(&ws[OFF_CESUM + na], ce);
        } else {
            ws[OFF_LAB + ((bid - NW_CLS) * RPW + r)] = s;   // label as float
        }
    }
    if (is_cls) {
        #pragma unroll
        for (int off = 32; off > 0; off >>= 1) nb += __shfl_xor(nb, off, 64);
        if (lane == 0) ws[OFF_NOOBJ + bid] = nb;    // non-atomic slot
    }
}

// 48 blocks x 64 threads, one object per thread: scattered gathers spread
// across 48 CUs (vs R4's single-CU latency wall). CE corrections atomicAdd
// straight into cesum; gt into global; a0..a3 wave-reduced -> 4 atomics/blk.
__global__ __launch_bounds__(64) void yolo_assign(
        const float* __restrict__ conf,
        const float* __restrict__ pred_xy,
        const float* __restrict__ pred_wh,
        const float* __restrict__ cls_score,
        const float* __restrict__ true_object,
        float* __restrict__ ws) {
    const float AW[5] = {0.57273f, 1.87446f, 3.33843f, 7.88282f, 9.77052f};
    const float AH[5] = {0.677385f, 2.06253f, 5.47434f, 3.52778f, 9.16828f};
    const int idx = blockIdx.x * 64 + threadIdx.x;  // 0..3071 exact
    float* cesum = ws + OFF_CESUM;
    float* gt    = ws + OFF_GT;

    int lab = (int)(ws[OFF_LAB + idx] + 0.5f);
    int b = idx / Md;
    const float4 to = ((const float4*)true_object)[idx];
    const float inv_ds = 1.0f / 32.0f;
    float gx = to.x * inv_ds, gy = to.y * inv_ds;
    float gw = to.z * inv_ds, gh = to.w * inv_ds;
    int ci = (int)gy, cj = (int)gx;                 // trunc == astype(int32)
    int cell = ci * 19 + cj;
    float garea = gw * gh;

    float best_iou = -1.0f; int best = 0; bool over[5];
    #pragma unroll
    for (int a = 0; a < 5; a++) {
        float inter = fminf(AW[a], gw) * fminf(AH[a], gh);
        float iou = inter / (AW[a] * AH[a] + garea - inter + EPSF);
        over[a] = iou > IOU_THRF;
        if (iou > best_iou) { best_iou = iou; best = a; }
    }

    int base_bn = (b * Nd + cell) * 5;
    float pwb = pred_wh[(size_t)(base_bn + best) * 2 + 0];
    float phb = pred_wh[(size_t)(base_bn + best) * 2 + 1];
    float inter = fminf(pwb, gw) * fminf(phb, gh);
    float iou_pg = inter / (pwb * phb + garea - inter + EPSF);
    float sw = 2.0f - (gw * (1.0f / 19.0f)) * (gh * (1.0f / 19.0f));

    float a0 = 0.f, a1 = 0.f, a2 = 0.f, a3 = 0.f;
    #pragma unroll
    for (int a = 0; a < 5; a++) {
        bool isb = (a == best);
        if (!(isb || over[a])) continue;            // om == 0 -> untouched
        int pos = base_bn + a;
        int na  = cell * 5 + a;
        float cp = fminf(fmaxf(conf[pos], EPSF), 1.0f - EPSF);
        a0 += __logf(1.0f - cp);                    // cancel base noobj term
        const float* cs = cls_score + (size_t)pos * Cd;
        atomicAdd(&cesum[na], cs[Cd - 1] - cs[lab]);
        if (isb) {
            atomicAdd(&gt[na], 1.0f);
            a1 += -(iou_pg * __logf(cp) + (1.0f - iou_pg) * __logf(1.0f - cp));
            float px = pred_xy[(size_t)pos * 2 + 0], py = pred_xy[(size_t)pos * 2 + 1];
            a2 += sw * ((px - gx) * (px - gx) + (py - gy) * (py - gy));
            float pwa = pred_wh[(size_t)pos * 2 + 0], pha = pred_wh[(size_t)pos * 2 + 1];
            a3 += sw * ((pwa - gw) * (pwa - gw) + (pha - gh) * (pha - gh));
        }
    }

    #pragma unroll
    for (int off = 32; off > 0; off >>= 1) {
        a0 += __shfl_xor(a0, off, 64);
        a1 += __shfl_xor(a1, off, 64);
        a2 += __shfl_xor(a2, off, 64);
        a3 += __shfl_xor(a3, off, 64);
    }
    if (threadIdx.x == 0) {
        atomicAdd(&ws[OFF_ACC + 0], a0);
        atomicAdd(&ws[OFF_ACC + 1], a1);
        atomicAdd(&ws[OFF_ACC + 2], a2);
        atomicAdd(&ws[OFF_ACC + 3], a3);
    }
}

// Single block, coalesced L2-resident reductions only (~60 KB of reads).
__global__ __launch_bounds__(1024) void yolo_reduce(
        const float* __restrict__ ws, float* __restrict__ out) {
    __shared__ float red[2][16];
    const int tid = threadIdx.x;
    float nsum = 0.0f;
    for (int i = tid; i < NW_CLS; i += 1024) nsum += ws[OFF_NOOBJ + i];
    float ssum = 0.0f;
    for (int na = tid; na < NAd; na += 1024)
        ssum += ws[OFF_GT + na] * ws[OFF_CESUM + na];

    float v[2] = {nsum, ssum};
    #pragma unroll
    for (int k = 0; k < 2; k++) {
        float x = v[k];
        #pragma unroll
        for (int off = 32; off > 0; off >>= 1) x += __shfl_xor(x, off, 64);
        if ((tid & 63) == 0) red[k][tid >> 6] = x;
    }
    __syncthreads();
    if (tid == 0) {
        float t0 = 0.f, t1 = 0.f;
        #pragma unroll
        for (int w = 0; w < 16; w++) { t0 += red[0][w]; t1 += red[1][w]; }
        const float invB = 1.0f / (float)Bsz;
        float noobj = 1.0f * (t0 + ws[OFF_ACC + 0]) * invB;   // base + cancels
        float obj   = 5.0f * ws[OFF_ACC + 1] * invB;
        float xy    = 5.0f * ws[OFF_ACC + 2] * invB;
        float wh    = 5.0f * ws[OFF_ACC + 3] * invB;
        float score = 5.0f * t1 * invB;
        out[0] = noobj + obj + xy + wh + score;
        out[1] = noobj;
        out[2] = obj;
        out[3] = score;
        out[4] = xy;
        out[5] = wh;
    }
}

extern "C" void kernel_launch(void* const* d_in, const int* in_sizes, int n_in,
                              void* d_out, int out_size, void* d_ws, size_t ws_size,
                              hipStream_t stream) {
    // inputs: 0=epoch(unused), 1=conf, 2=pred_xy, 3=pred_wh, 4=cls_score,
    //         5=true_label, 6=true_object, 7=fm_cord(unused - cancels out)
    const float* conf    = (const float*)d_in[1];
    const float* pred_xy = (const float*)d_in[2];
    const float* pred_wh = (const float*)d_in[3];
    const float* cls     = (const float*)d_in[4];
    const float* tlabel  = (const float*)d_in[5];
    const float* tobject = (const float*)d_in[6];
    float* ws  = (float*)d_ws;
    float* out = (float*)d_out;

    hipMemsetAsync(ws, 0, MEMSET_FLOATS * sizeof(float), stream);

    yolo_sweep<<<NW_CLS + NW_LAB, 64, 0, stream>>>(conf, cls, tlabel, ws);

    yolo_assign<<<NOBJ / 64, 64, 0, stream>>>(conf, pred_xy, pred_wh, cls, tobject, ws);

    yolo_reduce<<<1, 1024, 0, stream>>>(ws, out);
}

// Round 6
// 135.291 us; speedup vs baseline: 1.5545x; 1.0180x over previous
//
#include <hip/hip_runtime.h>

#define Bsz 128
#define Cd 81
#define Md 24
#define Nd 361
#define NAd 1805
#define TOTPOS 231040            // Bsz*NAd
#define RPW 16                   // rows per chunk
#define NCHUNK_CLS (TOTPOS/RPW)  // 14440 cls chunks
#define NOBJ (Bsz*Md)            // 3072
#define NCHUNK_TOT (NCHUNK_CLS + NOBJ/RPW)   // +192 label chunks = 14632
#define NBLK 4096                // persistent sweep blocks (16/CU)
#define EPSF 1e-7f
#define IOU_THRF 0.6f

// ws float layout:
//   [0 .. 1805)            cesum[NAd]   (sweep base CE + assign corrections)
//   [1808 .. 1812)         acc: 0=noobj-cancel, 1=obj, 2=xy, 3=wh
//   [1824 .. 3629)         gt[NAd]
//   [4096 .. 4096+NBLK)    noobj partial per sweep block (written unconditionally)
//   [20480 .. 20480+3072)  label (as float, written unconditionally)
#define OFF_CESUM 0
#define OFF_ACC   1808
#define OFF_GT    1824
#define OFF_NOOBJ 4096
#define OFF_LAB   20480
#define MEMSET_FLOATS 3629

#define EXP4(v) { v.x=__expf(v.x); v.y=__expf(v.y); v.z=__expf(v.z); v.w=__expf(v.w); }

// Persistent one-wave blocks, software-pipelined: while chunk k's 1296 floats
// are reduced out of LDS, chunk k+1's 6 float4-loads/lane are already in
// flight. No __syncthreads anywhere (single-wave block: DS pipe is in-order
// per wave, so the LDS write->read needs no barrier -- a barrier would emit
// s_waitcnt vmcnt(0) and drain the prefetch). Last 192 chunks process
// true_label rows (one-hot dot with class index) instead of sum-exp.
__global__ __launch_bounds__(64) void yolo_sweep(
        const float* __restrict__ conf,
        const float* __restrict__ cls_score,
        const float* __restrict__ true_label,
        float* __restrict__ ws) {
    __shared__ float ex[RPW * Cd];              // 5184 B
    const int lane = threadIdx.x;
    const int r = lane >> 2, h = lane & 3;
    float nb = 0.0f;

    int c = blockIdx.x;                         // first chunk (NBLK < NCHUNK_TOT)
    {   // prologue load (blockIdx < 4096 -> always a cls chunk)
    }
    const float4* g = (const float4*)(cls_score + (size_t)c * (RPW * Cd));
    float4 u0 = g[0 * 64 + lane];
    float4 u1 = g[1 * 64 + lane];
    float4 u2 = g[2 * 64 + lane];
    float4 u3 = g[3 * 64 + lane];
    float4 u4 = g[4 * 64 + lane];
    float4 u5 = g[260 + lane];                  // tail overlap [260,324)
    float cf = 0.0f;
    if (lane < RPW) cf = conf[c * RPW + lane];

    while (c < NCHUNK_TOT) {
        const bool is_cls = c < NCHUNK_CLS;
        if (is_cls) { EXP4(u0); EXP4(u1); EXP4(u2); EXP4(u3); EXP4(u4); EXP4(u5); }
        float4* l4 = (float4*)ex;
        l4[0 * 64 + lane] = u0;
        l4[1 * 64 + lane] = u1;
        l4[2 * 64 + lane] = u2;
        l4[3 * 64 + lane] = u3;
        l4[4 * 64 + lane] = u4;
        l4[260 + lane] = u5;                    // duplicates carry identical data
        __builtin_amdgcn_wave_barrier();        // pin ds_write before prefetch/reads

        // ---- prefetch next chunk (overlaps the whole reduce below) ----
        const int cn = c + NBLK;
        float4 n0 = {}, n1 = {}, n2 = {}, n3 = {}, n4 = {}, n5 = {};
        float cfn = 0.0f;
        if (cn < NCHUNK_TOT) {
            const float* srcn = (cn < NCHUNK_CLS)
                ? (cls_score + (size_t)cn * (RPW * Cd))
                : (true_label + (size_t)(cn - NCHUNK_CLS) * (RPW * Cd));
            const float4* gn = (const float4*)srcn;
            n0 = gn[0 * 64 + lane];
            n1 = gn[1 * 64 + lane];
            n2 = gn[2 * 64 + lane];
            n3 = gn[3 * 64 + lane];
            n4 = gn[4 * 64 + lane];
            n5 = gn[260 + lane];
            if (cn < NCHUNK_CLS && lane < RPW) cfn = conf[cn * RPW + lane];
        }

        // ---- reduce current chunk from LDS: 4 lanes per row ----
        const float* p = ex + r * Cd;
        float s = 0.0f;
        #pragma unroll
        for (int j = 0; j < 21; j++) {
            int c0 = h * 21 + j;
            int cc = c0 < 81 ? c0 : 80;         // stay in-bounds
            float w = (c0 < 81) ? (is_cls ? 1.0f : (float)c0) : 0.0f;
            s += p[cc] * w;
        }
        s += __shfl_xor(s, 1, 64);
        s += __shfl_xor(s, 2, 64);

        if (is_cls) {
            if (lane < RPW) {
                float cp = fminf(fmaxf(cf, EPSF), 1.0f - EPSF);
                nb += -__logf(1.0f - cp);
            }
            if (h == 0) {
                int row = c * RPW + r;          // row = b*NAd + na
                int na = row % NAd;
                float ce = __logf(s) - __logf(p[80]);   // lse - raw cs[80]
                atomicAdd(&ws[OFF_CESUM + na], ce);
            }
        } else {
            if (h == 0) ws[OFF_LAB + ((c - NCHUNK_CLS) * RPW + r)] = s;
        }

        u0 = n0; u1 = n1; u2 = n2; u3 = n3; u4 = n4; u5 = n5; cf = cfn;
        c = cn;
    }

    #pragma unroll
    for (int off = 32; off > 0; off >>= 1) nb += __shfl_xor(nb, off, 64);
    if (lane == 0) ws[OFF_NOOBJ + blockIdx.x] = nb;     // non-atomic slot
}

// 48 blocks x 64 threads, one object per thread: scattered gathers spread
// across 48 CUs. CE corrections atomicAdd straight into cesum; gt into
// global; a0..a3 wave-reduced -> 4 atomics/block.
__global__ __launch_bounds__(64) void yolo_assign(
        const float* __restrict__ conf,
        const float* __restrict__ pred_xy,
        const float* __restrict__ pred_wh,
        const float* __restrict__ cls_score,
        const float* __restrict__ true_object,
        float* __restrict__ ws) {
    const float AW[5] = {0.57273f, 1.87446f, 3.33843f, 7.88282f, 9.77052f};
    const float AH[5] = {0.677385f, 2.06253f, 5.47434f, 3.52778f, 9.16828f};
    const int idx = blockIdx.x * 64 + threadIdx.x;  // 0..3071 exact
    float* cesum = ws + OFF_CESUM;
    float* gt    = ws + OFF_GT;

    int lab = (int)(ws[OFF_LAB + idx] + 0.5f);
    int b = idx / Md;
    const float4 to = ((const float4*)true_object)[idx];
    const float inv_ds = 1.0f / 32.0f;
    float gx = to.x * inv_ds, gy = to.y * inv_ds;
    float gw = to.z * inv_ds, gh = to.w * inv_ds;
    int ci = (int)gy, cj = (int)gx;                 // trunc == astype(int32)
    int cell = ci * 19 + cj;
    float garea = gw * gh;

    float best_iou = -1.0f; int best = 0; bool over[5];
    #pragma unroll
    for (int a = 0; a < 5; a++) {
        float inter = fminf(AW[a], gw) * fminf(AH[a], gh);
        float iou = inter / (AW[a] * AH[a] + garea - inter + EPSF);
        over[a] = iou > IOU_THRF;
        if (iou > best_iou) { best_iou = iou; best = a; }
    }

    int base_bn = (b * Nd + cell) * 5;
    float pwb = pred_wh[(size_t)(base_bn + best) * 2 + 0];
    float phb = pred_wh[(size_t)(base_bn + best) * 2 + 1];
    float inter = fminf(pwb, gw) * fminf(phb, gh);
    float iou_pg = inter / (pwb * phb + garea - inter + EPSF);
    float sw = 2.0f - (gw * (1.0f / 19.0f)) * (gh * (1.0f / 19.0f));

    float a0 = 0.f, a1 = 0.f, a2 = 0.f, a3 = 0.f;
    #pragma unroll
    for (int a = 0; a < 5; a++) {
        bool isb = (a == best);
        if (!(isb || over[a])) continue;            // om == 0 -> untouched
        int pos = base_bn + a;
        int na  = cell * 5 + a;
        float cp = fminf(fmaxf(conf[pos], EPSF), 1.0f - EPSF);
        a0 += __logf(1.0f - cp);                    // cancel base noobj term
        const float* cs = cls_score + (size_t)pos * Cd;
        atomicAdd(&cesum[na], cs[Cd - 1] - cs[lab]);
        if (isb) {
            atomicAdd(&gt[na], 1.0f);
            a1 += -(iou_pg * __logf(cp) + (1.0f - iou_pg) * __logf(1.0f - cp));
            float px = pred_xy[(size_t)pos * 2 + 0], py = pred_xy[(size_t)pos * 2 + 1];
            a2 += sw * ((px - gx) * (px - gx) + (py - gy) * (py - gy));
            float pwa = pred_wh[(size_t)pos * 2 + 0], pha = pred_wh[(size_t)pos * 2 + 1];
            a3 += sw * ((pwa - gw) * (pwa - gw) + (pha - gh) * (pha - gh));
        }
    }

    #pragma unroll
    for (int off = 32; off > 0; off >>= 1) {
        a0 += __shfl_xor(a0, off, 64);
        a1 += __shfl_xor(a1, off, 64);
        a2 += __shfl_xor(a2, off, 64);
        a3 += __shfl_xor(a3, off, 64);
    }
    if (threadIdx.x == 0) {
        atomicAdd(&ws[OFF_ACC + 0], a0);
        atomicAdd(&ws[OFF_ACC + 1], a1);
        atomicAdd(&ws[OFF_ACC + 2], a2);
        atomicAdd(&ws[OFF_ACC + 3], a3);
    }
}

// Single block, coalesced L2-resident reductions only.
__global__ __launch_bounds__(1024) void yolo_reduce(
        const float* __restrict__ ws, float* __restrict__ out) {
    __shared__ float red[2][16];
    const int tid = threadIdx.x;
    float nsum = 0.0f;
    for (int i = tid; i < NBLK; i += 1024) nsum += ws[OFF_NOOBJ + i];
    float ssum = 0.0f;
    for (int na = tid; na < NAd; na += 1024)
        ssum += ws[OFF_GT + na] * ws[OFF_CESUM + na];

    float v[2] = {nsum, ssum};
    #pragma unroll
    for (int k = 0; k < 2; k++) {
        float x = v[k];
        #pragma unroll
        for (int off = 32; off > 0; off >>= 1) x += __shfl_xor(x, off, 64);
        if ((tid & 63) == 0) red[k][tid >> 6] = x;
    }
    __syncthreads();
    if (tid == 0) {
        float t0 = 0.f, t1 = 0.f;
        #pragma unroll
        for (int w = 0; w < 16; w++) { t0 += red[0][w]; t1 += red[1][w]; }
        const float invB = 1.0f / (float)Bsz;
        float noobj = 1.0f * (t0 + ws[OFF_ACC + 0]) * invB;   // base + cancels
        float obj   = 5.0f * ws[OFF_ACC + 1] * invB;
        float xy    = 5.0f * ws[OFF_ACC + 2] * invB;
        float wh    = 5.0f * ws[OFF_ACC + 3] * invB;
        float score = 5.0f * t1 * invB;
        out[0] = noobj + obj + xy + wh + score;
        out[1] = noobj;
        out[2] = obj;
        out[3] = score;
        out[4] = xy;
        out[5] = wh;
    }
}

extern "C" void kernel_launch(void* const* d_in, const int* in_sizes, int n_in,
                              void* d_out, int out_size, void* d_ws, size_t ws_size,
                              hipStream_t stream) {
    // inputs: 0=epoch(unused), 1=conf, 2=pred_xy, 3=pred_wh, 4=cls_score,
    //         5=true_label, 6=true_object, 7=fm_cord(unused - cancels out)
    const float* conf    = (const float*)d_in[1];
    const float* pred_xy = (const float*)d_in[2];
    const float* pred_wh = (const float*)d_in[3];
    const float* cls     = (const float*)d_in[4];
    const float* tlabel  = (const float*)d_in[5];
    const float* tobject = (const float*)d_in[6];
    float* ws  = (float*)d_ws;
    float* out = (float*)d_out;

    hipMemsetAsync(ws, 0, MEMSET_FLOATS * sizeof(float), stream);

    yolo_sweep<<<NBLK, 64, 0, stream>>>(conf, cls, tlabel, ws);

    yolo_assign<<<NOBJ / 64, 64, 0, stream>>>(conf, pred_xy, pred_wh, cls, tobject, ws);

    yolo_reduce<<<1, 1024, 0, stream>>>(ws, out);
}

// Round 7
// 130.812 us; speedup vs baseline: 1.6078x; 1.0342x over previous
//
#include <hip/hip_runtime.h>

#define Bsz 128
#define Cd 81
#define Md 24
#define Nd 361
#define NAd 1805
#define RPW 16                    // na-rows per tile / rows per chunk
#define NT 113                    // na tiles (112 full + 1 ragged, na0=1789)
#define NBLK_CLS (NT*16)          // 1808 cls blocks: (tile t, b-group g of 8)
#define NOBJ (Bsz*Md)             // 3072
#define NBLK_LAB (NOBJ/RPW)       // 192 label blocks
#define EPSF 1e-7f
#define IOU_THRF 0.6f

// ws float layout:
//   [0 .. 1805)        corr[NAd]      assign CE corrections (memset)
//   [1824 .. 3629)     gt[NAd]        (memset)
//   [3648 .. 3652)     acc: 0=noobj-cancel, 1=obj, 2=xy, 3=wh (memset)
//   [4096 .. 32976)    part[NAd][16]  CE partial per (na, b-group) - plain stores,
//                                     every slot written exactly once, no init
//   [33024 .. 34832)   noobj slot per cls block (written unconditionally)
//   [35072 .. 38144)   label (as float, written unconditionally)
#define OFF_CORR  0
#define OFF_GT    1824
#define OFF_ACC   3648
#define MEMSET_FLOATS 3652
#define OFF_PART  4096
#define OFF_NOOBJ 33024
#define OFF_LAB   35072

#define EXP4(v) { v.x=__expf(v.x); v.y=__expf(v.y); v.z=__expf(v.z); v.w=__expf(v.w); }

// Transposed sweep: block (t,g) owns na-tile [na0,na0+16) and b in [8g,8g+8).
// Each chunk (one b) = 1296 contiguous floats, loaded through an aligned
// float4 window (+m offset) into LDS, exp in registers, 4-lane row reduce;
// the 16 per-na CE values accumulate in REGISTERS across the 8 b's and are
// written with 16 plain stores. ZERO global atomics (the R2-R6 plateau was
// 231k same-line atomicAdds into cesum[1805] serializing at the TCC).
// 8-deep prefetch pipeline, single-wave blocks, no __syncthreads.
__global__ __launch_bounds__(64) void yolo_sweep(
        const float* __restrict__ conf,
        const float* __restrict__ cls_score,
        const float* __restrict__ true_label,
        float* __restrict__ ws) {
    __shared__ float ex[1300];                  // 325 float4s: window + m slack
    const int lane = threadIdx.x;
    const int r = lane >> 2, h = lane & 3;
    const int bid = blockIdx.x;
    float4* l4 = (float4*)ex;

    if (bid < NBLK_CLS) {
        const int t = bid >> 4, g = bid & 15;
        const int na0 = (t == NT - 1) ? (NAd - RPW) : t * RPW;   // ragged tail overlaps
        const int vmin = t * RPW;
        const bool validr = (na0 + r) >= vmin;               // row owned by this tile
        const bool validc = (lane < RPW) && ((na0 + lane) >= vmin);

        float accCE = 0.0f, nb = 0.0f;

        // prologue: b = 8g
        size_t s = ((size_t)(g * 8) * NAd + na0) * Cd;
        size_t a0 = s & ~(size_t)3;
        int mcur = (int)(s & 3);
        const float4* gp = (const float4*)cls_score + (a0 >> 2);
        float4 u0 = gp[0 * 64 + lane];
        float4 u1 = gp[1 * 64 + lane];
        float4 u2 = gp[2 * 64 + lane];
        float4 u3 = gp[3 * 64 + lane];
        float4 u4 = gp[4 * 64 + lane];
        float4 u5 = gp[261 + lane];             // covers [261,325); <=16B overread, page-safe
        float cf = validc ? conf[(size_t)(g * 8) * NAd + na0 + lane] : 0.5f;

        for (int it = 0; it < 8; ++it) {
            EXP4(u0); EXP4(u1); EXP4(u2); EXP4(u3); EXP4(u4); EXP4(u5);
            l4[0 * 64 + lane] = u0;
            l4[1 * 64 + lane] = u1;
            l4[2 * 64 + lane] = u2;
            l4[3 * 64 + lane] = u3;
            l4[4 * 64 + lane] = u4;
            l4[261 + lane] = u5;                // dup region carries identical data
            __builtin_amdgcn_wave_barrier();

            // ---- prefetch next b (overlaps the reduce) ----
            float4 n0 = {}, n1 = {}, n2 = {}, n3 = {}, n4 = {}, n5 = {};
            float cfn = 0.0f; int mnext = 0;
            if (it < 7) {
                int b = g * 8 + it + 1;
                s = ((size_t)b * NAd + na0) * Cd;
                a0 = s & ~(size_t)3;
                mnext = (int)(s & 3);
                gp = (const float4*)cls_score + (a0 >> 2);
                n0 = gp[0 * 64 + lane];
                n1 = gp[1 * 64 + lane];
                n2 = gp[2 * 64 + lane];
                n3 = gp[3 * 64 + lane];
                n4 = gp[4 * 64 + lane];
                n5 = gp[261 + lane];
                cfn = validc ? conf[(size_t)b * NAd + na0 + lane] : 0.5f;
            }

            // ---- reduce current chunk: 4 lanes per row ----
            const float* p = ex + mcur + r * Cd;
            float sacc = 0.0f;
            #pragma unroll
            for (int j = 0; j < 21; j++) {
                int c0 = h * 21 + j;
                int cc = c0 < 81 ? c0 : 80;
                float w = (c0 < 81) ? 1.0f : 0.0f;
                sacc += p[cc] * w;
            }
            sacc += __shfl_xor(sacc, 1, 64);
            sacc += __shfl_xor(sacc, 2, 64);
            if (h == 0 && validr)
                accCE += __logf(sacc) - __logf(p[80]);      // lse - raw cs[80]
            if (validc) {
                float cp = fminf(fmaxf(cf, EPSF), 1.0f - EPSF);
                nb += -__logf(1.0f - cp);
            }

            u0 = n0; u1 = n1; u2 = n2; u3 = n3; u4 = n4; u5 = n5;
            cf = cfn; mcur = mnext;
        }

        if (h == 0 && validr)
            ws[OFF_PART + (size_t)(na0 + r) * 16 + g] = accCE;   // unique slot, plain store

        #pragma unroll
        for (int off = 32; off > 0; off >>= 1) nb += __shfl_xor(nb, off, 64);
        if (lane == 0) ws[OFF_NOOBJ + bid] = nb;
    } else {
        // label block: 16 contiguous one-hot rows (1296 floats, aligned)
        const int lb = bid - NBLK_CLS;
        const float4* gp = (const float4*)(true_label + (size_t)lb * (RPW * Cd));
        float4 u0 = gp[0 * 64 + lane];
        float4 u1 = gp[1 * 64 + lane];
        float4 u2 = gp[2 * 64 + lane];
        float4 u3 = gp[3 * 64 + lane];
        float4 u4 = gp[4 * 64 + lane];
        float4 u5 = gp[260 + lane];             // covers [260,324)
        l4[0 * 64 + lane] = u0;
        l4[1 * 64 + lane] = u1;
        l4[2 * 64 + lane] = u2;
        l4[3 * 64 + lane] = u3;
        l4[4 * 64 + lane] = u4;
        l4[260 + lane] = u5;
        __builtin_amdgcn_wave_barrier();
        const float* p = ex + r * Cd;
        float sacc = 0.0f;
        #pragma unroll
        for (int j = 0; j < 21; j++) {
            int c0 = h * 21 + j;
            int cc = c0 < 81 ? c0 : 80;
            float w = (c0 < 81) ? (float)c0 : 0.0f;   // one-hot dot class index
            sacc += p[cc] * w;
        }
        sacc += __shfl_xor(sacc, 1, 64);
        sacc += __shfl_xor(sacc, 2, 64);
        if (h == 0) ws[OFF_LAB + lb * RPW + r] = sacc;
    }
}

// 48 blocks x 64 threads, one object per thread: scattered gathers spread
// across 48 CUs. Corrections -> corr[] (15k atomics, ~8/addr: cheap);
// gt -> global; a0..a3 wave-reduced -> 4 atomics/block.
__global__ __launch_bounds__(64) void yolo_assign(
        const float* __restrict__ conf,
        const float* __restrict__ pred_xy,
        const float* __restrict__ pred_wh,
        const float* __restrict__ cls_score,
        const float* __restrict__ true_object,
        float* __restrict__ ws) {
    const float AW[5] = {0.57273f, 1.87446f, 3.33843f, 7.88282f, 9.77052f};
    const float AH[5] = {0.677385f, 2.06253f, 5.47434f, 3.52778f, 9.16828f};
    const int idx = blockIdx.x * 64 + threadIdx.x;  // 0..3071 exact
    float* corr = ws + OFF_CORR;
    float* gt   = ws + OFF_GT;

    int lab = (int)(ws[OFF_LAB + idx] + 0.5f);
    int b = idx / Md;
    const float4 to = ((const float4*)true_object)[idx];
    const float inv_ds = 1.0f / 32.0f;
    float gx = to.x * inv_ds, gy = to.y * inv_ds;
    float gw = to.z * inv_ds, gh = to.w * inv_ds;
    int ci = (int)gy, cj = (int)gx;                 // trunc == astype(int32)
    int cell = ci * 19 + cj;
    float garea = gw * gh;

    float best_iou = -1.0f; int best = 0; bool over[5];
    #pragma unroll
    for (int a = 0; a < 5; a++) {
        float inter = fminf(AW[a], gw) * fminf(AH[a], gh);
        float iou = inter / (AW[a] * AH[a] + garea - inter + EPSF);
        over[a] = iou > IOU_THRF;
        if (iou > best_iou) { best_iou = iou; best = a; }
    }

    int base_bn = (b * Nd + cell) * 5;
    float pwb = pred_wh[(size_t)(base_bn + best) * 2 + 0];
    float phb = pred_wh[(size_t)(base_bn + best) * 2 + 1];
    float inter = fminf(pwb, gw) * fminf(phb, gh);
    float iou_pg = inter / (pwb * phb + garea - inter + EPSF);
    float sw = 2.0f - (gw * (1.0f / 19.0f)) * (gh * (1.0f / 19.0f));

    float a0 = 0.f, a1 = 0.f, a2 = 0.f, a3 = 0.f;
    #pragma unroll
    for (int a = 0; a < 5; a++) {
        bool isb = (a == best);
        if (!(isb || over[a])) continue;            // om == 0 -> untouched
        int pos = base_bn + a;
        int na  = cell * 5 + a;
        float cp = fminf(fmaxf(conf[pos], EPSF), 1.0f - EPSF);
        a0 += __logf(1.0f - cp);                    // cancel base noobj term
        const float* cs = cls_score + (size_t)pos * Cd;
        atomicAdd(&corr[na], cs[Cd - 1] - cs[lab]);
        if (isb) {
            atomicAdd(&gt[na], 1.0f);
            a1 += -(iou_pg * __logf(cp) + (1.0f - iou_pg) * __logf(1.0f - cp));
            float px = pred_xy[(size_t)pos * 2 + 0], py = pred_xy[(size_t)pos * 2 + 1];
            a2 += sw * ((px - gx) * (px - gx) + (py - gy) * (py - gy));
            float pwa = pred_wh[(size_t)pos * 2 + 0], pha = pred_wh[(size_t)pos * 2 + 1];
            a3 += sw * ((pwa - gw) * (pwa - gw) + (pha - gh) * (pha - gh));
        }
    }

    #pragma unroll
    for (int off = 32; off > 0; off >>= 1) {
        a0 += __shfl_xor(a0, off, 64);
        a1 += __shfl_xor(a1, off, 64);
        a2 += __shfl_xor(a2, off, 64);
        a3 += __shfl_xor(a3, off, 64);
    }
    if (threadIdx.x == 0) {
        atomicAdd(&ws[OFF_ACC + 0], a0);
        atomicAdd(&ws[OFF_ACC + 1], a1);
        atomicAdd(&ws[OFF_ACC + 2], a2);
        atomicAdd(&ws[OFF_ACC + 3], a3);
    }
}

// Single block, coalesced L2-resident reductions only (~140 KB of reads).
__global__ __launch_bounds__(1024) void yolo_reduce(
        const float* __restrict__ ws, float* __restrict__ out) {
    __shared__ float red[2][16];
    const int tid = threadIdx.x;
    float nsum = 0.0f;
    for (int i = tid; i < NBLK_CLS; i += 1024) nsum += ws[OFF_NOOBJ + i];
    float ssum = 0.0f;
    const float4* part4 = (const float4*)(ws + OFF_PART);
    for (int na = tid; na < NAd; na += 1024) {
        float4 p0 = part4[na * 4 + 0];
        float4 p1 = part4[na * 4 + 1];
        float4 p2 = part4[na * 4 + 2];
        float4 p3 = part4[na * 4 + 3];
        float ce = p0.x + p0.y + p0.z + p0.w + p1.x + p1.y + p1.z + p1.w
                 + p2.x + p2.y + p2.z + p2.w + p3.x + p3.y + p3.z + p3.w
                 + ws[OFF_CORR + na];
        ssum += ws[OFF_GT + na] * ce;
    }

    float v[2] = {nsum, ssum};
    #pragma unroll
    for (int k = 0; k < 2; k++) {
        float x = v[k];
        #pragma unroll
        for (int off = 32; off > 0; off >>= 1) x += __shfl_xor(x, off, 64);
        if ((tid & 63) == 0) red[k][tid >> 6] = x;
    }
    __syncthreads();
    if (tid == 0) {
        float t0 = 0.f, t1 = 0.f;
        #pragma unroll
        for (int w = 0; w < 16; w++) { t0 += red[0][w]; t1 += red[1][w]; }
        const float invB = 1.0f / (float)Bsz;
        float noobj = 1.0f * (t0 + ws[OFF_ACC + 0]) * invB;   // base + cancels
        float obj   = 5.0f * ws[OFF_ACC + 1] * invB;
        float xy    = 5.0f * ws[OFF_ACC + 2] * invB;
        float wh    = 5.0f * ws[OFF_ACC + 3] * invB;
        float score = 5.0f * t1 * invB;
        out[0] = noobj + obj + xy + wh + score;
        out[1] = noobj;
        out[2] = obj;
        out[3] = score;
        out[4] = xy;
        out[5] = wh;
    }
}

extern "C" void kernel_launch(void* const* d_in, const int* in_sizes, int n_in,
                              void* d_out, int out_size, void* d_ws, size_t ws_size,
                              hipStream_t stream) {
    // inputs: 0=epoch(unused), 1=conf, 2=pred_xy, 3=pred_wh, 4=cls_score,
    //         5=true_label, 6=true_object, 7=fm_cord(unused - cancels out)
    const float* conf    = (const float*)d_in[1];
    const float* pred_xy = (const float*)d_in[2];
    const float* pred_wh = (const float*)d_in[3];
    const float* cls     = (const float*)d_in[4];
    const float* tlabel  = (const float*)d_in[5];
    const float* tobject = (const float*)d_in[6];
    float* ws  = (float*)d_ws;
    float* out = (float*)d_out;

    hipMemsetAsync(ws, 0, MEMSET_FLOATS * sizeof(float), stream);

    yolo_sweep<<<NBLK_CLS + NBLK_LAB, 64, 0, stream>>>(conf, cls, tlabel, ws);

    yolo_assign<<<NOBJ / 64, 64, 0, stream>>>(conf, pred_xy, pred_wh, cls, tobject, ws);

    yolo_reduce<<<1, 1024, 0, stream>>>(ws, out);
}